// Round 7
// baseline (304.173 us; speedup 1.0000x reference)
//
#include <hip/hip_runtime.h>
#include <hip/hip_bf16.h>

namespace {

constexpr int B_   = 4;
constexpr int CIN  = 64;
constexpr int COUT = 128;
constexpr int HIN  = 64,  WIN  = 1024;
constexpr int HOUT = 32,  WOUT = 512;
constexpr int TW   = 32;        // wo positions per block (r7: 16 -> 32, halves per-position Wc/x overhead)
constexpr int KTOT = CIN * 16;  // 1024

typedef __bf16 bf16x8 __attribute__((ext_vector_type(8)));
typedef float  f32x4  __attribute__((ext_vector_type(4)));

// wcb[o][tap*64+c] = Wc[o][c*16+tap] (bf16);  w2t[c][c1] = W2[c1][c] (bf16)
__global__ void cvt_wts(const float* __restrict__ Wc, const float* __restrict__ W2,
                        __hip_bfloat16* __restrict__ wcb, __hip_bfloat16* __restrict__ w2t) {
    int i = blockIdx.x * 256 + threadIdx.x;
    if (i < COUT * KTOT) {
        int o = i >> 10, k = i & 1023, tap = k >> 6, c = k & 63;
        wcb[i] = __float2bfloat16(Wc[(size_t)o * KTOT + c * 16 + tap]);
    } else if (i < COUT * KTOT + CIN * CIN) {
        int m = i - COUT * KTOT;
        int c = m >> 6, c1 = m & 63;
        w2t[m] = __float2bfloat16(W2[c1 * CIN + c]);
    }
}

// r0-r6: time invariant (~215-225us) under every micro-knob (conflicts -78%,
// VGPR 64-84, load order, setprio, LDS size) -> the cost is per-BLOCK
// structural streaming: every block re-streams the full 256KB WcB (fragment
// loads touch 16 lines/instr) and re-fetches the x halo. TW=32 halves the
// block count -> halves per-position Wc/x/fixed costs. 512 threads, 8 waves.
// LDS = 32 pos x 2KB = 64KB exactly -> 2 blocks/CU, 16 waves/CU ceiling
// (> the ~10.6 measured at TW=16).
__global__ __launch_bounds__(512, 2)
void fused_ccconv(const float* __restrict__ x,  const float* __restrict__ r,
                  const float* __restrict__ W1, const float* __restrict__ b1,
                  const __hip_bfloat16* __restrict__ W2T, const float* __restrict__ b2,
                  const __hip_bfloat16* __restrict__ WcB, const float* __restrict__ bc,
                  float* __restrict__ out)
{
    // Per position p (2 KiB region): phase 1b writes w[row][col] at
    //   elem = row*64 + (col ^ ((row&7)<<2))           (8B-chunk XOR swizzle)
    // phase 1c overwrites the same region with A[tap][c] at
    //   byte = tap*128 + ((chunk16*16) ^ (((tap^p)&7)<<4))
    // Each w row is read (wrow) ONLY by the same lane that overwrites it with A,
    // and 1b/1c for a position live on the same wave -> in-order DS, no barrier.
    __shared__ __hip_bfloat16 S[TW * 1024];   // 65,536 B exactly

    const int t   = threadIdx.x;
    // XCD swizzle: grid 2048 = 8 XCDs x 256. Blocks sharing x rows (same b,ho;
    // adjacent wt) get contiguous wid on ONE XCD -> x halo hits its L2, not L3.
    const int bx  = blockIdx.x;
    const int wid = ((bx & 7) << 8) | (bx >> 3);   // bijective on [0,2048)
    const int wt  = wid & 15;          // WOUT/TW = 16 tiles
    const int ho  = (wid >> 4) & 31;
    const int b   = wid >> 9;
    const int wo0 = wt * TW;

    const float* rb = r + (size_t)b * HIN * WIN;

    // ---- output 1: r_center ----
    if (t < TW) {
        const int wo = wo0 + t;
        out[(size_t)B_*COUT*HOUT*WOUT + ((size_t)b*HOUT + ho)*WOUT + wo] =
            rb[(2*ho + 1)*WIN + (2*wo + 1)];
    }

    const int ln   = t & 63;
    const int wv   = t >> 6;           // 0..7
    const int lm   = ln & 15;
    const int quad = ln >> 4;

    const float AZI = 0.006135923151542565f;  // 2*pi/1024
    const float INC = 0.0073f;

    // ================= phase 1b: w = leaky(pe@W1+b1)@W2 + b2 via MFMA =================
    {
        // B-frags (W2T) from global, L1-hot: lane holds W2T[nt*16+lm][k..k+7]
        bf16x8 bfr[4][2];
        float  b2v[4];
        #pragma unroll
        for (int nt = 0; nt < 4; ++nt) {
            #pragma unroll
            for (int ks = 0; ks < 2; ++ks)
                bfr[nt][ks] = *reinterpret_cast<const bf16x8*>(
                    W2T + (nt*16 + lm)*CIN + ks*32 + quad*8);
            b2v[nt] = b2[nt*16 + lm];
        }

        // this lane's tap (A-operand row) = lm
        const int i_ = lm >> 2, j_ = lm & 3;
        const float di = (float)(i_ - 2), dj = (float)(j_ - 2);
        const float cA = cosf(AZI * dj), sA = sinf(AZI * dj);
        const float cI = cosf(INC * di), sI = sinf(INC * di);
        const int hsrc = (2*ho + j_ + 63) & 63;

        #pragma unroll
        for (int mt = 0; mt < 4; ++mt) {
            const int p  = wv*4 + mt;          // 0..31: 8 waves x 4 = 32 positions
            const int wo = wo0 + p;
            const int wsrc = 2*wo + i_ - 1;
            const bool inb = (unsigned)wsrc < (unsigned)WIN;
            const float rpv = inb ? rb[hsrc*WIN + wsrc] : 100.0f;
            const float rc  = rb[(2*ho + 1)*WIN + (2*wo + 1)];
            const float pe0 = rpv * cA * cI - rc;
            const float pe1 = rpv * cA * sI;
            const float pe2 = rpv * sA;

            // A-frags: lane holds h[tap=lm][c1 = ks*32 + quad*8 + j]
            bf16x8 af0, af1;
            #pragma unroll
            for (int ks = 0; ks < 2; ++ks) {
                const int cb = ks*32 + quad*8;
                #pragma unroll
                for (int j = 0; j < 8; ++j) {
                    const int c1 = cb + j;
                    float hv = fmaf(pe0, W1[c1],
                               fmaf(pe1, W1[CIN + c1],
                               fmaf(pe2, W1[2*CIN + c1], b1[c1])));
                    hv = (hv >= 0.0f) ? hv : 0.2f * hv;
                    __hip_bfloat16 hb = __float2bfloat16(hv);
                    if (ks == 0) af0[j] = *reinterpret_cast<__bf16*>(&hb);
                    else         af1[j] = *reinterpret_cast<__bf16*>(&hb);
                }
            }

            #pragma unroll
            for (int nt = 0; nt < 4; ++nt) {
                f32x4 acc = {b2v[nt], b2v[nt], b2v[nt], b2v[nt]};
                acc = __builtin_amdgcn_mfma_f32_16x16x32_bf16(af0, bfr[nt][0], acc, 0, 0, 0);
                acc = __builtin_amdgcn_mfma_f32_16x16x32_bf16(af1, bfr[nt][1], acc, 0, 0, 0);
                // D: row(tap) = quad*4+q, col(c) = nt*16+lm -> w[row][col],
                // stored with 8B-chunk XOR swizzle within the 128B row
                #pragma unroll
                for (int q = 0; q < 4; ++q) {
                    const int row = quad*4 + q;
                    S[p*1024 + row*64 + ((nt*16 + lm) ^ ((row & 7) << 2))] =
                        __float2bfloat16(acc[q]);
                }
            }
        }
    }

    // ================= phase 1c: A[p][tap*64+c] = w[tap][c] * x =================
    {
        const int p   = t >> 4;        // 0..31 (512 threads = 32 pos x 16 taps)
        const int tap = t & 15;
        const int i_  = tap >> 2, j_ = tap & 3;
        const int hsrc = (2*ho + j_ + 63) & 63;
        const int wo   = wo0 + p;
        const int wsrc = 2*wo + i_ - 1;
        const bool inb = (unsigned)wsrc < (unsigned)WIN;

        const float* xb = x + (size_t)b*CIN*HIN*WIN + hsrc*WIN + wsrc;

        // prefetch all x (short live ranges; r0-r6: no spill)
        float xall[CIN];
        #pragma unroll
        for (int c = 0; c < CIN; ++c)
            xall[c] = inb ? xb[(size_t)c * HIN * WIN] : 0.0f;

        // read this row's w: logical 8B chunk u sits at physical chunk u^(tap&7)
        const int ws = tap & 7;
        uint2 wrow[16];
        const uint2* wp = reinterpret_cast<const uint2*>(S + p*1024 + tap*64);
        #pragma unroll
        for (int u = 0; u < 16; ++u) wrow[u] = wp[u ^ ws];

        // A-writes: 16B chunk g -> physical chunk g ^ ((tap^p)&7)
        const int swz = ((tap ^ p) & 7) << 4;
        char* Abase = reinterpret_cast<char*>(S + p*1024) + tap*128;

        #pragma unroll
        for (int g = 0; g < 8; ++g) {
            uint pk[4];
            #pragma unroll
            for (int pr = 0; pr < 4; ++pr) {
                const int c0 = g*8 + pr*2;
                const uint2 wv2 = wrow[c0 >> 2];
                const uint word = (c0 & 2) ? wv2.y : wv2.x;
                const float w0 = __uint_as_float(word << 16);
                const float w1 = __uint_as_float(word & 0xffff0000u);
                __hip_bfloat16 p0 = __float2bfloat16(w0 * xall[c0]);
                __hip_bfloat16 p1 = __float2bfloat16(w1 * xall[c0 + 1]);
                const uint lo = *reinterpret_cast<unsigned short*>(&p0);
                const uint hi = *reinterpret_cast<unsigned short*>(&p1);
                pk[pr] = lo | (hi << 16);
            }
            *reinterpret_cast<uint4*>(Abase + ((g*16) ^ swz)) =
                make_uint4(pk[0], pk[1], pk[2], pk[3]);
        }
    }

    __syncthreads();

    // ================= phase 2: out[o][p] = bc[o] + sum_k Wc[o][k']*A[p][k'] =================
    {
        // 8 waves: wave wv -> outputs o0 = (wv>>1)*32, position group pg = wv&1.
        // Wc stream (256KB/block) now amortized over 32 positions (was 16).
        const int o0 = (wv >> 1) * 32;
        const int p2 = (wv & 1) * 16 + lm;   // this lane's position 0..31
        const __hip_bfloat16* wcP0 = WcB + ((size_t)(o0 + lm)) * KTOT + quad*8;
        const __hip_bfloat16* wcP1 = wcP0 + (size_t)16 * KTOT;
        const char* aRow = reinterpret_cast<const char*>(S) + p2*2048;
        const int qoff = quad << 4;

        f32x4 acc0 = {0.f,0.f,0.f,0.f};
        f32x4 acc1 = {0.f,0.f,0.f,0.f};

        #pragma unroll 8
        for (int ks = 0; ks < KTOT/32; ++ks) {
            const int tap = ks >> 1;
            const int rem = ((ks & 1) << 6) + qoff;   // logical byte offset in tap row
            const bf16x8 af = *reinterpret_cast<const bf16x8*>(
                aRow + tap*128 + (rem ^ (((tap ^ p2) & 7) << 4)));  // matches writer
            const bf16x8 w0 = *reinterpret_cast<const bf16x8*>(wcP0 + ks*32);
            const bf16x8 w1 = *reinterpret_cast<const bf16x8*>(wcP1 + ks*32);
            acc0 = __builtin_amdgcn_mfma_f32_16x16x32_bf16(w0, af, acc0, 0, 0, 0);
            acc1 = __builtin_amdgcn_mfma_f32_16x16x32_bf16(w1, af, acc1, 0, 0, 0);
        }

        #pragma unroll
        for (int q = 0; q < 4; ++q) {
            const int oa = o0 + quad*4 + q;
            const int ob = oa + 16;
            out[(((size_t)b*COUT + oa)*HOUT + ho)*WOUT + wo0 + p2] = acc0[q] + bc[oa];
            out[(((size_t)b*COUT + ob)*HOUT + ho)*WOUT + wo0 + p2] = acc1[q] + bc[ob];
        }
    }
}

} // namespace

extern "C" void kernel_launch(void* const* d_in, const int* in_sizes, int n_in,
                              void* d_out, int out_size, void* d_ws, size_t ws_size,
                              hipStream_t stream) {
    const float* x  = (const float*)d_in[0];
    const float* r  = (const float*)d_in[1];
    const float* W1 = (const float*)d_in[2];
    const float* b1 = (const float*)d_in[3];
    const float* W2 = (const float*)d_in[4];
    const float* b2 = (const float*)d_in[5];
    const float* Wc = (const float*)d_in[6];
    const float* bc = (const float*)d_in[7];
    float* out = (float*)d_out;

    __hip_bfloat16* wcb = (__hip_bfloat16*)d_ws;                       // 256 KB
    __hip_bfloat16* w2t = (__hip_bfloat16*)((char*)d_ws + 262144);     // 8 KB

    const int ntot = COUT*KTOT + CIN*CIN;   // 135168
    hipLaunchKernelGGL(cvt_wts, dim3((ntot + 255)/256), dim3(256), 0, stream,
                       Wc, W2, wcb, w2t);

    dim3 grid(B_ * HOUT * (WOUT / TW));   // 2048
    dim3 block(512);
    hipLaunchKernelGGL(fused_ccconv, grid, block, 0, stream,
                       x, r, W1, b1, w2t, b2, wcb, bc, out);
}